// Round 8
// baseline (181.463 us; speedup 1.0000x reference)
//
#include <hip/hip_runtime.h>

typedef unsigned short u16;
typedef unsigned int u32;
typedef __attribute__((ext_vector_type(8))) __bf16 bf16x8;
typedef __attribute__((ext_vector_type(4))) float f32x4;

#define B_SZ   2
#define S_LEN  2048
#define E_DIM  1024
#define NHEAD  16
#define HD     64
#define KDIM   1024

__device__ __forceinline__ float bf2f(u16 u){
  union { u32 i; float f; } c; c.i = ((u32)u) << 16; return c.f;
}
__device__ __forceinline__ u16 f2bf(float f){
  union { float f; u32 i; } c; c.f = f;
  return (u16)((c.i + 0x7FFFu + ((c.i >> 16) & 1u)) >> 16);
}
__device__ __forceinline__ u16 f2bf_fast(float f){
  union { float f; u32 i; } c; c.f = f;
  return (u16)((c.i + 0x8000u) >> 16);
}
__device__ __forceinline__ void gl2lds16(const void* g, void* l){
  __builtin_amdgcn_global_load_lds((const __attribute__((address_space(1))) void*)g,
                                   (__attribute__((address_space(3))) void*)l, 16, 0, 0);
}

// ---------------- prep: z<4 -> W_z transpose+cast (swizzled); z>=4 -> x cast (swizzled) ----------------
__global__ __launch_bounds__(256) void prep_kernel(const float* __restrict__ x,
                                                   const float* __restrict__ Wq, const float* __restrict__ Wk,
                                                   const float* __restrict__ Wv, const float* __restrict__ Wg,
                                                   u16* __restrict__ xb, u16* __restrict__ WT){
  __shared__ u16 tile[64][66];
  int z = blockIdx.z;
  int t = threadIdx.x;
  if (z < 4){
    const float* Ws[4] = {Wq, Wk, Wv, Wg};
    const float* W = Ws[z];
    int n0 = blockIdx.x * 64, k0 = blockIdx.y * 64;
    int r = t >> 2, cg = (t & 3) * 16;
    const float* src = W + (size_t)(k0 + r) * E_DIM + n0 + cg;
    float f[16];
    #pragma unroll
    for (int c = 0; c < 4; c++) *(float4*)&f[c * 4] = *(const float4*)&src[c * 4];
    #pragma unroll
    for (int i = 0; i < 16; i++) tile[r][cg + i] = f2bf(f[i]);
    __syncthreads();
    u16 ov[16];
    #pragma unroll
    for (int i = 0; i < 16; i++) ov[i] = tile[cg + i][r];
    int n7 = r & 7, cb = cg >> 3;
    u16* dst = WT + (size_t)(z * E_DIM + n0 + r) * KDIM + k0;
    *(uint4*)&dst[(cb ^ n7) * 8]       = *(uint4*)&ov[0];
    *(uint4*)&dst[((cb + 1) ^ n7) * 8] = *(uint4*)&ov[8];
  } else {
    int blk = (z - 4) * 256 + blockIdx.y * 16 + blockIdx.x;
    size_t flat = ((size_t)blk * 256 + t) * 16;
    int m7 = (int)((flat >> 10) & 7);
    int cb = (int)((flat >> 3) & 7);
    size_t tl = flat & ~(size_t)63;
    float f[16];
    #pragma unroll
    for (int c = 0; c < 4; c++) *(float4*)&f[c * 4] = *(const float4*)&x[flat + c * 4];
    u16 o[16];
    #pragma unroll
    for (int i = 0; i < 16; i++) o[i] = f2bf(f[i]);
    *(uint4*)&xb[tl + ((cb ^ m7) * 8)]       = *(uint4*)&o[0];
    *(uint4*)&xb[tl + (((cb + 1) ^ m7) * 8)] = *(uint4*)&o[8];
  }
}

// ---------------- fused QKVG GEMM + rotary/transpose epilogue (LDS-staged stores) ----------------
// Main loop: 256x256 tile, BK=64, Gray-code 3-subphase; safe gating (single vmcnt(0) at XC-end,
// R6 race post-mortem). Epilogue: chained-rotation rotary + LDS-staged coalesced stores.
__global__ __launch_bounds__(512, 2) void gemm_kernel(const u16* __restrict__ A, const u16* __restrict__ Bt,
                                                      u16* __restrict__ qr, u16* __restrict__ kr,
                                                      u16* __restrict__ vt, u16* __restrict__ gc){
  __shared__ __align__(16) u16 SH[65536];   // 128 KB: main loop As/Bs; epilogue staging
  int m0 = blockIdx.y * 256, n0 = blockIdx.x * 256;
  int t = threadIdx.x;
  int wave = t >> 6, lane = t & 63;
  int l15 = lane & 15, quad = lane >> 4, h8 = lane & 7;
  int wm = wave >> 2, wn = wave & 3;

  f32x4 acc[8][4];
  #pragma unroll
  for (int i = 0; i < 8; i++)
    #pragma unroll
    for (int j = 0; j < 4; j++) acc[i][j] = (f32x4){0.f, 0.f, 0.f, 0.f};

  auto Aoff = [&](int buf, int half) -> int { return (buf * 2 + half) * 8192; };
  auto Boff = [&](int buf, int half) -> int { return 32768 + (buf * 2 + half) * 8192; };

  auto stA = [&](int buf, int half, int kt){
    const u16* src = A + (size_t)(m0 + half * 128) * KDIM + kt * 64;
    #pragma unroll
    for (int c = 0; c < 2; c++){
      int L = c * 512 + t;
      gl2lds16(src + (size_t)(L >> 3) * KDIM + (L & 7) * 8, &SH[Aoff(buf, half) + L * 8]);
    }
  };
  auto stB = [&](int buf, int half, int kt){
    const u16* src = Bt + (size_t)(n0 + half * 128) * KDIM + kt * 64;
    #pragma unroll
    for (int c = 0; c < 2; c++){
      int L = c * 512 + t;
      gl2lds16(src + (size_t)(L >> 3) * KDIM + (L & 7) * 8, &SH[Boff(buf, half) + L * 8]);
    }
  };
  auto ldA = [&](int buf, int i, int ks) -> bf16x8 {
    int r = i * 16 + l15;
    return *(const bf16x8*)&SH[Aoff(buf, wm) + r * 64 + (((ks * 4 + quad) ^ h8) * 8)];
  };
  auto ldB = [&](int buf, int j, int ks) -> bf16x8 {
    int c = (wn & 1) * 64 + j * 16 + l15;
    return *(const bf16x8*)&SH[Boff(buf, wn >> 1) + c * 64 + (((ks * 4 + quad) ^ h8) * 8)];
  };

  stA(0, 0, 0); stB(0, 0, 0); stA(0, 1, 0); stB(0, 1, 0);
  asm volatile("s_waitcnt vmcnt(0)" ::: "memory");
  __builtin_amdgcn_s_barrier();

  bf16x8 a[4][2];
  bf16x8 bA[2][2];
  bf16x8 bB[2][2];

  for (int t2 = 0; t2 < 8; ++t2){
    int kt0 = 2 * t2;
    bool more = (t2 < 7);

    #pragma unroll
    for (int half = 0; half < 2; ++half){
      int buf = half;
      bool stg = (buf == 0) || more;
      // ---------- XA: a0 + b0 | stage oth.Ah0 + oth.Bh0 | q1 ----------
      {
        #pragma unroll
        for (int i = 0; i < 4; i++){ a[i][0] = ldA(buf, i, 0); a[i][1] = ldA(buf, i, 1); }
        #pragma unroll
        for (int j = 0; j < 2; j++){ bA[j][0] = ldB(buf, j, 0); bA[j][1] = ldB(buf, j, 1); }
        if (buf == 0){ stA(1, 0, kt0 + 1); stB(1, 0, kt0 + 1); }
        else if (more){ stA(0, 0, kt0 + 2); stB(0, 0, kt0 + 2); }
        __builtin_amdgcn_sched_barrier(0);
        __builtin_amdgcn_s_barrier();
        asm volatile("s_waitcnt lgkmcnt(0)" ::: "memory");
        __builtin_amdgcn_sched_barrier(0);
        __builtin_amdgcn_s_setprio(1);
        #pragma unroll
        for (int i = 0; i < 4; i++)
          #pragma unroll
          for (int j = 0; j < 2; j++){
            acc[i][j] = __builtin_amdgcn_mfma_f32_16x16x32_bf16(a[i][0], bA[j][0], acc[i][j], 0, 0, 0);
            acc[i][j] = __builtin_amdgcn_mfma_f32_16x16x32_bf16(a[i][1], bA[j][1], acc[i][j], 0, 0, 0);
          }
        __builtin_amdgcn_s_setprio(0);
        __builtin_amdgcn_sched_barrier(0);
        __builtin_amdgcn_s_barrier();
      }
      // ---------- XB: b1 | stage oth.Ah1 + oth.Bh1 | q2 ----------
      {
        #pragma unroll
        for (int j = 0; j < 2; j++){ bB[j][0] = ldB(buf, j + 2, 0); bB[j][1] = ldB(buf, j + 2, 1); }
        if (buf == 0){ stA(1, 1, kt0 + 1); stB(1, 1, kt0 + 1); }
        else if (more){ stA(0, 1, kt0 + 2); stB(0, 1, kt0 + 2); }
        __builtin_amdgcn_sched_barrier(0);
        __builtin_amdgcn_s_barrier();
        asm volatile("s_waitcnt lgkmcnt(0)" ::: "memory");
        __builtin_amdgcn_sched_barrier(0);
        __builtin_amdgcn_s_setprio(1);
        #pragma unroll
        for (int i = 0; i < 4; i++)
          #pragma unroll
          for (int j = 0; j < 2; j++){
            acc[i][j + 2] = __builtin_amdgcn_mfma_f32_16x16x32_bf16(a[i][0], bB[j][0], acc[i][j + 2], 0, 0, 0);
            acc[i][j + 2] = __builtin_amdgcn_mfma_f32_16x16x32_bf16(a[i][1], bB[j][1], acc[i][j + 2], 0, 0, 0);
          }
        __builtin_amdgcn_s_setprio(0);
        __builtin_amdgcn_sched_barrier(0);
        __builtin_amdgcn_s_barrier();
      }
      // ---------- XC: a1 | no stage | q3 + q4 | vmcnt(0) while stages exist ----------
      {
        #pragma unroll
        for (int i = 0; i < 4; i++){ a[i][0] = ldA(buf, i + 4, 0); a[i][1] = ldA(buf, i + 4, 1); }
        __builtin_amdgcn_sched_barrier(0);
        __builtin_amdgcn_s_barrier();
        asm volatile("s_waitcnt lgkmcnt(0)" ::: "memory");
        __builtin_amdgcn_sched_barrier(0);
        __builtin_amdgcn_s_setprio(1);
        #pragma unroll
        for (int i = 0; i < 4; i++)
          #pragma unroll
          for (int j = 0; j < 2; j++){
            acc[i + 4][j + 2] = __builtin_amdgcn_mfma_f32_16x16x32_bf16(a[i][0], bB[j][0], acc[i + 4][j + 2], 0, 0, 0);
            acc[i + 4][j + 2] = __builtin_amdgcn_mfma_f32_16x16x32_bf16(a[i][1], bB[j][1], acc[i + 4][j + 2], 0, 0, 0);
          }
        #pragma unroll
        for (int i = 0; i < 4; i++)
          #pragma unroll
          for (int j = 0; j < 2; j++){
            acc[i + 4][j] = __builtin_amdgcn_mfma_f32_16x16x32_bf16(a[i][0], bA[j][0], acc[i + 4][j], 0, 0, 0);
            acc[i + 4][j] = __builtin_amdgcn_mfma_f32_16x16x32_bf16(a[i][1], bA[j][1], acc[i + 4][j], 0, 0, 0);
          }
        __builtin_amdgcn_s_setprio(0);
        __builtin_amdgcn_sched_barrier(0);
        if (stg) { asm volatile("s_waitcnt vmcnt(0)" ::: "memory"); }
        __builtin_amdgcn_s_barrier();
      }
    }
  }

  // ---------------- fused epilogue (LDS-staged) ----------------
  __syncthreads();
  u16* epi = SH + wave * 8192;
  int zone = n0 >> 10;          // 0=q, 1=k, 2=v, 3=g
  int n0l = n0 & 1023;
  int hh = (n0l >> 6) + wn;
  int b = m0 >> 11;
  int s0f = (m0 & 2047) + wm * 128;

  if (zone == 2){
    // V: epi rows = d (64 x 128 u16); chunk position = (s>>3)^(d&7) == vt's global layout
    #pragma unroll
    for (int j = 0; j < 4; j++){
      int d = j * 16 + l15;
      #pragma unroll
      for (int i = 0; i < 8; i++){
        int cs0 = i * 2 + (quad >> 1);            // logical s-chunk
        u16 pk[4];
        #pragma unroll
        for (int r = 0; r < 4; r++) pk[r] = f2bf(acc[i][j][r]);
        *(uint2*)&epi[d * 128 + ((cs0 ^ (d & 7)) * 8) + (quad & 1) * 4] = *(uint2*)pk;
      }
    }
    __syncthreads();
    int dl = lane >> 4, cl = lane & 15;
    size_t vbase = (size_t)((b << 4) + hh) * HD * S_LEN;
    #pragma unroll
    for (int it = 0; it < 16; it++){
      int d = it * 4 + dl;
      uint4 v = *(const uint4*)&epi[d * 128 + cl * 8];   // identity copy (layouts match)
      *(uint4*)&vt[vbase + (size_t)d * S_LEN + s0f + cl * 8] = v;
    }
  } else if (zone == 3){
    #pragma unroll
    for (int j = 0; j < 4; j++){
      int c0c = 2 * j + (l15 >> 3), o7 = l15 & 7;
      #pragma unroll
      for (int i = 0; i < 8; i++)
        #pragma unroll
        for (int r = 0; r < 4; r++){
          int row = i * 16 + quad * 4 + r;
          epi[row * 64 + ((c0c ^ (row & 7)) * 8) + o7] = f2bf(acc[i][j][r]);
        }
    }
    __syncthreads();
    int rl = lane >> 3, cl = lane & 7;
    #pragma unroll
    for (int it = 0; it < 16; it++){
      int row = it * 8 + rl;
      uint4 v = *(const uint4*)&epi[row * 64 + ((cl ^ (row & 7)) * 8)];
      *(uint4*)&gc[(size_t)(m0 + wm * 128 + row) * E_DIM + n0l + wn * 64 + cl * 8] = v;
    }
  } else {
    // q / k: chained-rotation rotary, staged in epi rows = s (128 x 64 u16),
    // chunk position (d>>3)^(s&7) == kr's global layout (and the bank-conflict fix for q)
    float scale = (zone == 1) ? 0.03125f : 1.0f;
    float sgn = (l15 & 1) ? 1.0f : -1.0f;
    #pragma unroll
    for (int j = 0; j < 4; j++){
      int d = j * 16 + l15;
      int c0c = 2 * j + (l15 >> 3), o7 = l15 & 7;
      float af = exp2f(-(float)(d >> 1) * (13.287712379549449f / 31.0f));
      float cs, sn, ca1, sa1, cb, sb_;
      __sincosf((float)(s0f + quad * 4) * af, &sn, &cs);
      __sincosf(af, &sa1, &ca1);
      __sincosf(13.0f * af, &sb_, &cb);
      #pragma unroll
      for (int i = 0; i < 8; i++)
        #pragma unroll
        for (int r = 0; r < 4; r++){
          int row = i * 16 + quad * 4 + r;
          float vv = acc[i][j][r] * scale;
          float p = __shfl_xor(vv, 1);
          float outv = vv * cs + sgn * p * sn;
          epi[row * 64 + ((c0c ^ (row & 7)) * 8) + o7] = f2bf(outv);
          float nc, ns;
          if (r < 3){ nc = cs * ca1 - sn * sa1; ns = sn * ca1 + cs * sa1; }
          else      { nc = cs * cb  - sn * sb_; ns = sn * cb  + cs * sb_; }
          cs = nc; sn = ns;
        }
    }
    __syncthreads();
    int rl = lane >> 3, cl = lane & 7;
    size_t qkbase = (size_t)((b << 4) + hh) * S_LEN + s0f;
    u16* dst = (zone == 0) ? qr : kr;
    #pragma unroll
    for (int it = 0; it < 16; it++){
      int row = it * 8 + rl;
      int rp = (zone == 0) ? (cl ^ (row & 7)) : cl;    // q deswizzles; k layouts match
      uint4 v = *(const uint4*)&epi[row * 64 + rp * 8];
      *(uint4*)&dst[(qkbase + row) * HD + cl * 8] = v;
    }
  }
}

// ---------------- retention (transpose world): S^T = K Q^T, O^T = V^T P^T ----------------
// PIPELINE v2 (T3/T4, 3-buffer ring + counted vmcnt, LDS 66KB -> 2 blocks/CU unchanged):
//   prologue: stage t0,t1 -> vmcnt(4) (t0 landed, t1 in flight) -> barrier
//   iter kb:  stage t(kb+2) into slot (cur+2)%3  [that slot's last reads were 2 barriers ago: WAR-safe]
//             compute slot cur
//             gate: vmcnt(4) if staged this iter else vmcnt(0)  [drains t(kb+1); t(kb+2) stays
//             in flight and is NOT read until 2 iterations later -- legal counted group, unlike the
//             R6 gemm race where the counted-out group was needed immediately]
//             raw s_barrier (no full drain; Ps is wave-private so only DMA needs fencing).
// Replaces the 2-stage drain-0 __syncthreads loop (m233 pathology; m218: counted-vs-drain0 is the gain).
__global__ __launch_bounds__(256, 2) void retention_kernel(const u16* __restrict__ qr, const u16* __restrict__ kr,
                                                           const u16* __restrict__ vt,
                                                           u16* __restrict__ pO, u16* __restrict__ pBa){
  int bh = blockIdx.x;
  int qb = 15 - (int)blockIdx.y;
  int z  = blockIdx.z;
  int h = bh & 15;
  int q0 = qb * 128;
  __shared__ __align__(16) u16 Ks[3][4096];
  __shared__ __align__(16) u16 Vs[3][4096];
  __shared__ __align__(16) u16 Ps[128 * 72];
  int t = threadIdx.x, wave = t >> 6, lane = t & 63;
  int l15 = lane & 15, quad = lane >> 4, h8 = lane & 7;

  float decay = log1pf(-exp2f(-5.0f - (float)h));
  float negd = -decay;
  float estep = __expf(64.0f * negd);

  int qsE[2], rowb[2];
  #pragma unroll
  for (int e = 0; e < 2; e++){ rowb[e] = wave * 32 + e * 16; qsE[e] = q0 + rowb[e]; }

  bf16x8 qB[2][2];
  #pragma unroll
  for (int e = 0; e < 2; e++){
    size_t qrow = ((size_t)bh * S_LEN + qsE[e] + l15) * HD;
    qB[e][0] = *(const bf16x8*)&qr[qrow + quad * 8];
    qB[e][1] = *(const bf16x8*)&qr[qrow + 32 + quad * 8];
  }

  float win_f = 11.0f / negd;
  int win_i = (win_f > 2.1e9f) ? 0x7f000000 : (int)win_f;
  int nk = 2 * qb + 2;
  int z_lo = (z * nk) >> 2;
  int z_hi = (((z + 1) * nk) >> 2) - 1;
  int kb_lo = z_lo;
  {
    int jmin = q0 - win_i;
    if (jmin > z_lo * 64){ int wlo = jmin >> 6; kb_lo = wlo > z_lo ? wlo : z_lo; }
  }
  int k0s = kb_lo * 64;

  float em1d = expm1f(decay);
  float rfE[2]; int iE[2];
  #pragma unroll
  for (int e = 0; e < 2; e++){
    int i = qsE[e] + l15;
    iE[e] = i;
    float rowsum = expm1f((float)(i + 1) * decay) / em1d;
    rfE[e] = __expf((float)(i - k0s) * decay) * rsqrtf(rowsum);
  }
  float e1 = __expf(negd);
  float c16 = __expf(negd * 16.0f);
  float cbr[4];
  cbr[0] = __expf(negd * (float)(quad * 4));
  cbr[1] = cbr[0] * e1; cbr[2] = cbr[1] * e1; cbr[3] = cbr[2] * e1;

  f32x4 o[2][4];
  #pragma unroll
  for (int e = 0; e < 2; e++)
    #pragma unroll
    for (int dt = 0; dt < 4; dt++) o[e][dt] = (f32x4){0.f, 0.f, 0.f, 0.f};
  float babs[2] = {0.f, 0.f};

  const u16* krbh = kr + (size_t)bh * S_LEN * HD;
  const u16* vtbh = vt + (size_t)bh * HD * S_LEN;

  auto stKV = [&](int kb, int slot){
    int k0 = kb * 64;
    #pragma unroll
    for (int c = 0; c < 2; c++){
      int L = c * 256 + t;
      gl2lds16(krbh + (size_t)k0 * HD + L * 8, &Ks[slot][L * 8]);
    }
    #pragma unroll
    for (int c = 0; c < 2; c++){
      int L = c * 256 + t;
      gl2lds16(vtbh + (size_t)(L >> 3) * S_LEN + k0 + (L & 7) * 8, &Vs[slot][L * 8]);
    }
  };

  if (kb_lo <= z_hi){
    stKV(kb_lo, 0);
    if (kb_lo + 1 <= z_hi){
      stKV(kb_lo + 1, 1);
      asm volatile("s_waitcnt vmcnt(4)" ::: "memory");
    } else {
      asm volatile("s_waitcnt vmcnt(0)" ::: "memory");
    }
    __builtin_amdgcn_sched_barrier(0);
    __builtin_amdgcn_s_barrier();
    __builtin_amdgcn_sched_barrier(0);

    int cur = 0;
    for (int kb = kb_lo; kb <= z_hi; kb++){
      bool stg = (kb + 2 <= z_hi);
      if (stg) stKV(kb + 2, (cur + 2) % 3);

      int k0 = kb * 64;
      const u16* KsC = &Ks[cur][0];
      const u16* VsC = &Vs[cur][0];

      bf16x8 kA0[4], kA1[4];
      #pragma unroll
      for (int ct = 0; ct < 4; ct++){
        int rw = (ct * 16 + l15) * 64;
        kA0[ct] = *(const bf16x8*)&KsC[rw + ((quad ^ h8) * 8)];
        kA1[ct] = *(const bf16x8*)&KsC[rw + (((quad + 4) ^ h8) * 8)];
      }
      #pragma unroll
      for (int e = 0; e < 2; e++){
        int qs = qsE[e];
        if (k0 <= qs + 15 && k0 + 63 >= qs - win_i){
          bool diag = (k0 + 64 > qs);
          float cf[4] = {cbr[0], cbr[1], cbr[2], cbr[3]};
          #pragma unroll
          for (int ct = 0; ct < 4; ct++){
            f32x4 zacc = (f32x4){0.f, 0.f, 0.f, 0.f};
            zacc = __builtin_amdgcn_mfma_f32_16x16x32_bf16(kA0[ct], qB[e][0], zacc, 0, 0, 0);
            zacc = __builtin_amdgcn_mfma_f32_16x16x32_bf16(kA1[ct], qB[e][1], zacc, 0, 0, 0);
            u16 pk[4];
            #pragma unroll
            for (int r = 0; r < 4; r++){
              float p = zacc[r] * (rfE[e] * cf[r]);
              if (diag && (k0 + ct * 16 + quad * 4 + r) > iE[e]) p = 0.f;
              babs[e] += fabsf(p);
              pk[r] = f2bf_fast(p);
              cf[r] *= c16;
            }
            u32 lo = (u32)pk[0] | ((u32)pk[1] << 16);
            u32 hi = (u32)pk[2] | ((u32)pk[3] << 16);
            *(uint2*)&Ps[(rowb[e] + l15) * 72 + ct * 16 + quad * 4] = make_uint2(lo, hi);
          }
        }
      }
      #pragma unroll
      for (int e = 0; e < 2; e++){
        int qs = qsE[e];
        if (k0 <= qs + 15 && k0 + 63 >= qs - win_i){
          bf16x8 pB0 = *(const bf16x8*)&Ps[(rowb[e] + l15) * 72 + quad * 8];
          bf16x8 pB1 = *(const bf16x8*)&Ps[(rowb[e] + l15) * 72 + 32 + quad * 8];
          #pragma unroll
          for (int dt = 0; dt < 4; dt++){
            int rw = (dt * 16 + l15) * 64;
            bf16x8 vA0 = *(const bf16x8*)&VsC[rw + ((quad ^ h8) * 8)];
            bf16x8 vA1 = *(const bf16x8*)&VsC[rw + (((quad + 4) ^ h8) * 8)];
            o[e][dt] = __builtin_amdgcn_mfma_f32_16x16x32_bf16(vA0, pB0, o[e][dt], 0, 0, 0);
            o[e][dt] = __builtin_amdgcn_mfma_f32_16x16x32_bf16(vA1, pB1, o[e][dt], 0, 0, 0);
          }
        }
      }
      #pragma unroll
      for (int e = 0; e < 2; e++) rfE[e] *= estep;

      if (kb < z_hi){
        __builtin_amdgcn_sched_barrier(0);
        if (stg) { asm volatile("s_waitcnt vmcnt(4)" ::: "memory"); }
        else     { asm volatile("s_waitcnt vmcnt(0)" ::: "memory"); }
        __builtin_amdgcn_s_barrier();
        __builtin_amdgcn_sched_barrier(0);
      }
      cur = (cur == 2) ? 0 : cur + 1;
    }
  }

  size_t slot = ((size_t)bh * 16 + qb) * 4 + z;
  u16* po = pO + slot * (4 * 128 * 16);
  #pragma unroll
  for (int e = 0; e < 2; e++){
    float bsum = babs[e];
    bsum += __shfl_xor(bsum, 16);
    bsum += __shfl_xor(bsum, 32);
    if (quad == 0) pBa[slot * 128 + rowb[e] + l15] = f2bf(bsum);
    #pragma unroll
    for (int dt = 0; dt < 4; dt++){
      u16 pk[4];
      #pragma unroll
      for (int r = 0; r < 4; r++) pk[r] = f2bf(o[e][dt][r]);
      *(uint2*)&po[(dt * 128 + rowb[e] + l15) * 16 + quad * 4] = *(uint2*)pk;
    }
  }
}

// ---------------- combine: sum 4 partials, denom clip, RMS, SiLU(g) ----------------
__global__ __launch_bounds__(128) void combine_kernel(const u16* __restrict__ pO, const u16* __restrict__ pBa,
                                                      const u16* __restrict__ gc, float* __restrict__ out){
  int bh = blockIdx.x, qb = blockIdx.y;
  int b = bh >> 4, h = bh & 15;
  int i = threadIdx.x;
  int s = qb * 128 + i;
  size_t s4 = ((size_t)bh * 16 + qb) * 4;
  float v[64];
  #pragma unroll
  for (int d = 0; d < 64; d++) v[d] = 0.f;
  float bsum = 0.f;
  #pragma unroll
  for (int z = 0; z < 4; z++){
    const u16* pz = pO + (s4 + z) * 8192;
    #pragma unroll
    for (int dt = 0; dt < 4; dt++){
      u16 a[16];
      *(uint4*)&a[0] = *(const uint4*)&pz[(dt * 128 + i) * 16];
      *(uint4*)&a[8] = *(const uint4*)&pz[(dt * 128 + i) * 16 + 8];
      #pragma unroll
      for (int c = 0; c < 16; c++) v[dt * 16 + c] += bf2f(a[c]);
    }
    bsum += bf2f(pBa[(s4 + z) * 128 + i]);
  }
  float dinv = 1.0f / fminf(fmaxf(bsum, 1.0f), 50000.0f);
  float ssq = 0.f;
  #pragma unroll
  for (int d = 0; d < 64; d++){ v[d] *= dinv; ssq += v[d] * v[d]; }
  float rms = rsqrtf(ssq * (1.0f / 64.0f) + 1e-6f);
  size_t gbase = ((size_t)b * S_LEN + s) * E_DIM + h * HD;
  u16 gu[64];
  #pragma unroll
  for (int c = 0; c < 8; c++) *(uint4*)&gu[c * 8] = *(const uint4*)&gc[gbase + c * 8];
  float ov[64];
  #pragma unroll
  for (int d = 0; d < 64; d++){
    float gv = bf2f(gu[d]);
    float sg = gv / (1.0f + __expf(-gv));
    ov[d] = v[d] * rms * sg;
  }
  float* obase = out + ((size_t)b * S_LEN + s) * E_DIM + h * HD;
  #pragma unroll
  for (int c = 0; c < 16; c++) *(float4*)&obase[c * 4] = *(float4*)&ov[c * 4];
}

extern "C" void kernel_launch(void* const* d_in, const int* in_sizes, int n_in,
                              void* d_out, int out_size, void* d_ws, size_t ws_size,
                              hipStream_t stream){
  const float* x  = (const float*)d_in[0];
  const float* Wq = (const float*)d_in[1];
  const float* Wk = (const float*)d_in[2];
  const float* Wv = (const float*)d_in[3];
  const float* Wg = (const float*)d_in[4];
  float* out = (float*)d_out;
  char* ws = (char*)d_ws;
  // ws layout (stream-ordered overlays), 64.5 MB peak:
  //   [0,8M):   xb (dead after gemm)  \__ overlaid by pO [0,32M) written by retention
  //   [8,16M):  WT (dead after gemm)  /
  //   [32,40M): qr    [40,48M): kr    [48,56M): vt   (gemm out, retention in)
  //   [56,64M): gc (live until combine)
  //   [64,64.5M): pBa
  u16* xb  = (u16*)(ws);
  u16* WT  = (u16*)(ws + (8ull  << 20));
  u16* pO  = (u16*)(ws);
  u16* qrp = (u16*)(ws + (32ull << 20));
  u16* krp = (u16*)(ws + (40ull << 20));
  u16* vtp = (u16*)(ws + (48ull << 20));
  u16* gcp = (u16*)(ws + (56ull << 20));
  u16* pBa = (u16*)(ws + (64ull << 20));

  prep_kernel     <<<dim3(16, 16, 8),  256, 0, stream>>>(x, Wq, Wk, Wv, Wg, xb, WT);
  gemm_kernel     <<<dim3(16, 16),     512, 0, stream>>>(xb, WT, qrp, krp, vtp, gcp);
  retention_kernel<<<dim3(32, 16, 4),  256, 0, stream>>>(qrp, krp, vtp, pO, pBa);
  combine_kernel  <<<dim3(32, 16),     128, 0, stream>>>(pO, pBa, gcp, out);
}

// Round 9
// 175.959 us; speedup vs baseline: 1.0313x; 1.0313x over previous
//
#include <hip/hip_runtime.h>

typedef unsigned short u16;
typedef unsigned int u32;
typedef __attribute__((ext_vector_type(8))) __bf16 bf16x8;
typedef __attribute__((ext_vector_type(4))) float f32x4;

#define B_SZ   2
#define S_LEN  2048
#define E_DIM  1024
#define NHEAD  16
#define HD     64
#define KDIM   1024

__device__ __forceinline__ float bf2f(u16 u){
  union { u32 i; float f; } c; c.i = ((u32)u) << 16; return c.f;
}
__device__ __forceinline__ u16 f2bf(float f){
  union { float f; u32 i; } c; c.f = f;
  return (u16)((c.i + 0x7FFFu + ((c.i >> 16) & 1u)) >> 16);
}
__device__ __forceinline__ u16 f2bf_fast(float f){
  union { float f; u32 i; } c; c.f = f;
  return (u16)((c.i + 0x8000u) >> 16);
}
__device__ __forceinline__ void gl2lds16(const void* g, void* l){
  __builtin_amdgcn_global_load_lds((const __attribute__((address_space(1))) void*)g,
                                   (__attribute__((address_space(3))) void*)l, 16, 0, 0);
}

// ---------------- prep: z<4 -> W_z transpose+cast (swizzled); z>=4 -> x cast (swizzled) ----------------
__global__ __launch_bounds__(256) void prep_kernel(const float* __restrict__ x,
                                                   const float* __restrict__ Wq, const float* __restrict__ Wk,
                                                   const float* __restrict__ Wv, const float* __restrict__ Wg,
                                                   u16* __restrict__ xb, u16* __restrict__ WT){
  __shared__ u16 tile[64][66];
  int z = blockIdx.z;
  int t = threadIdx.x;
  if (z < 4){
    const float* Ws[4] = {Wq, Wk, Wv, Wg};
    const float* W = Ws[z];
    int n0 = blockIdx.x * 64, k0 = blockIdx.y * 64;
    int r = t >> 2, cg = (t & 3) * 16;
    const float* src = W + (size_t)(k0 + r) * E_DIM + n0 + cg;
    float f[16];
    #pragma unroll
    for (int c = 0; c < 4; c++) *(float4*)&f[c * 4] = *(const float4*)&src[c * 4];
    #pragma unroll
    for (int i = 0; i < 16; i++) tile[r][cg + i] = f2bf(f[i]);
    __syncthreads();
    u16 ov[16];
    #pragma unroll
    for (int i = 0; i < 16; i++) ov[i] = tile[cg + i][r];
    int n7 = r & 7, cb = cg >> 3;
    u16* dst = WT + (size_t)(z * E_DIM + n0 + r) * KDIM + k0;
    *(uint4*)&dst[(cb ^ n7) * 8]       = *(uint4*)&ov[0];
    *(uint4*)&dst[((cb + 1) ^ n7) * 8] = *(uint4*)&ov[8];
  } else {
    int blk = (z - 4) * 256 + blockIdx.y * 16 + blockIdx.x;
    size_t flat = ((size_t)blk * 256 + t) * 16;
    int m7 = (int)((flat >> 10) & 7);
    int cb = (int)((flat >> 3) & 7);
    size_t tl = flat & ~(size_t)63;
    float f[16];
    #pragma unroll
    for (int c = 0; c < 4; c++) *(float4*)&f[c * 4] = *(const float4*)&x[flat + c * 4];
    u16 o[16];
    #pragma unroll
    for (int i = 0; i < 16; i++) o[i] = f2bf(f[i]);
    *(uint4*)&xb[tl + ((cb ^ m7) * 8)]       = *(uint4*)&o[0];
    *(uint4*)&xb[tl + (((cb + 1) ^ m7) * 8)] = *(uint4*)&o[8];
  }
}

// ---------------- fused QKVG GEMM + rotary/transpose epilogue (LDS-staged stores) ----------------
// Main loop: 256x256 tile, BK=64, Gray-code 3-subphase; safe gating (single vmcnt(0) at XC-end,
// R6 race post-mortem). Epilogue: chained-rotation rotary + LDS-staged coalesced stores.
__global__ __launch_bounds__(512, 2) void gemm_kernel(const u16* __restrict__ A, const u16* __restrict__ Bt,
                                                      u16* __restrict__ qr, u16* __restrict__ kr,
                                                      u16* __restrict__ vt, u16* __restrict__ gc){
  __shared__ __align__(16) u16 SH[65536];   // 128 KB: main loop As/Bs; epilogue staging
  int m0 = blockIdx.y * 256, n0 = blockIdx.x * 256;
  int t = threadIdx.x;
  int wave = t >> 6, lane = t & 63;
  int l15 = lane & 15, quad = lane >> 4, h8 = lane & 7;
  int wm = wave >> 2, wn = wave & 3;

  f32x4 acc[8][4];
  #pragma unroll
  for (int i = 0; i < 8; i++)
    #pragma unroll
    for (int j = 0; j < 4; j++) acc[i][j] = (f32x4){0.f, 0.f, 0.f, 0.f};

  auto Aoff = [&](int buf, int half) -> int { return (buf * 2 + half) * 8192; };
  auto Boff = [&](int buf, int half) -> int { return 32768 + (buf * 2 + half) * 8192; };

  auto stA = [&](int buf, int half, int kt){
    const u16* src = A + (size_t)(m0 + half * 128) * KDIM + kt * 64;
    #pragma unroll
    for (int c = 0; c < 2; c++){
      int L = c * 512 + t;
      gl2lds16(src + (size_t)(L >> 3) * KDIM + (L & 7) * 8, &SH[Aoff(buf, half) + L * 8]);
    }
  };
  auto stB = [&](int buf, int half, int kt){
    const u16* src = Bt + (size_t)(n0 + half * 128) * KDIM + kt * 64;
    #pragma unroll
    for (int c = 0; c < 2; c++){
      int L = c * 512 + t;
      gl2lds16(src + (size_t)(L >> 3) * KDIM + (L & 7) * 8, &SH[Boff(buf, half) + L * 8]);
    }
  };
  auto ldA = [&](int buf, int i, int ks) -> bf16x8 {
    int r = i * 16 + l15;
    return *(const bf16x8*)&SH[Aoff(buf, wm) + r * 64 + (((ks * 4 + quad) ^ h8) * 8)];
  };
  auto ldB = [&](int buf, int j, int ks) -> bf16x8 {
    int c = (wn & 1) * 64 + j * 16 + l15;
    return *(const bf16x8*)&SH[Boff(buf, wn >> 1) + c * 64 + (((ks * 4 + quad) ^ h8) * 8)];
  };

  stA(0, 0, 0); stB(0, 0, 0); stA(0, 1, 0); stB(0, 1, 0);
  asm volatile("s_waitcnt vmcnt(0)" ::: "memory");
  __builtin_amdgcn_s_barrier();

  bf16x8 a[4][2];
  bf16x8 bA[2][2];
  bf16x8 bB[2][2];

  for (int t2 = 0; t2 < 8; ++t2){
    int kt0 = 2 * t2;
    bool more = (t2 < 7);

    #pragma unroll
    for (int half = 0; half < 2; ++half){
      int buf = half;
      bool stg = (buf == 0) || more;
      // ---------- XA: a0 + b0 | stage oth.Ah0 + oth.Bh0 | q1 ----------
      {
        #pragma unroll
        for (int i = 0; i < 4; i++){ a[i][0] = ldA(buf, i, 0); a[i][1] = ldA(buf, i, 1); }
        #pragma unroll
        for (int j = 0; j < 2; j++){ bA[j][0] = ldB(buf, j, 0); bA[j][1] = ldB(buf, j, 1); }
        if (buf == 0){ stA(1, 0, kt0 + 1); stB(1, 0, kt0 + 1); }
        else if (more){ stA(0, 0, kt0 + 2); stB(0, 0, kt0 + 2); }
        __builtin_amdgcn_sched_barrier(0);
        __builtin_amdgcn_s_barrier();
        asm volatile("s_waitcnt lgkmcnt(0)" ::: "memory");
        __builtin_amdgcn_sched_barrier(0);
        __builtin_amdgcn_s_setprio(1);
        #pragma unroll
        for (int i = 0; i < 4; i++)
          #pragma unroll
          for (int j = 0; j < 2; j++){
            acc[i][j] = __builtin_amdgcn_mfma_f32_16x16x32_bf16(a[i][0], bA[j][0], acc[i][j], 0, 0, 0);
            acc[i][j] = __builtin_amdgcn_mfma_f32_16x16x32_bf16(a[i][1], bA[j][1], acc[i][j], 0, 0, 0);
          }
        __builtin_amdgcn_s_setprio(0);
        __builtin_amdgcn_sched_barrier(0);
        __builtin_amdgcn_s_barrier();
      }
      // ---------- XB: b1 | stage oth.Ah1 + oth.Bh1 | q2 ----------
      {
        #pragma unroll
        for (int j = 0; j < 2; j++){ bB[j][0] = ldB(buf, j + 2, 0); bB[j][1] = ldB(buf, j + 2, 1); }
        if (buf == 0){ stA(1, 1, kt0 + 1); stB(1, 1, kt0 + 1); }
        else if (more){ stA(0, 1, kt0 + 2); stB(0, 1, kt0 + 2); }
        __builtin_amdgcn_sched_barrier(0);
        __builtin_amdgcn_s_barrier();
        asm volatile("s_waitcnt lgkmcnt(0)" ::: "memory");
        __builtin_amdgcn_sched_barrier(0);
        __builtin_amdgcn_s_setprio(1);
        #pragma unroll
        for (int i = 0; i < 4; i++)
          #pragma unroll
          for (int j = 0; j < 2; j++){
            acc[i][j + 2] = __builtin_amdgcn_mfma_f32_16x16x32_bf16(a[i][0], bB[j][0], acc[i][j + 2], 0, 0, 0);
            acc[i][j + 2] = __builtin_amdgcn_mfma_f32_16x16x32_bf16(a[i][1], bB[j][1], acc[i][j + 2], 0, 0, 0);
          }
        __builtin_amdgcn_s_setprio(0);
        __builtin_amdgcn_sched_barrier(0);
        __builtin_amdgcn_s_barrier();
      }
      // ---------- XC: a1 | no stage | q3 + q4 | vmcnt(0) while stages exist ----------
      {
        #pragma unroll
        for (int i = 0; i < 4; i++){ a[i][0] = ldA(buf, i + 4, 0); a[i][1] = ldA(buf, i + 4, 1); }
        __builtin_amdgcn_sched_barrier(0);
        __builtin_amdgcn_s_barrier();
        asm volatile("s_waitcnt lgkmcnt(0)" ::: "memory");
        __builtin_amdgcn_sched_barrier(0);
        __builtin_amdgcn_s_setprio(1);
        #pragma unroll
        for (int i = 0; i < 4; i++)
          #pragma unroll
          for (int j = 0; j < 2; j++){
            acc[i + 4][j + 2] = __builtin_amdgcn_mfma_f32_16x16x32_bf16(a[i][0], bB[j][0], acc[i + 4][j + 2], 0, 0, 0);
            acc[i + 4][j + 2] = __builtin_amdgcn_mfma_f32_16x16x32_bf16(a[i][1], bB[j][1], acc[i + 4][j + 2], 0, 0, 0);
          }
        #pragma unroll
        for (int i = 0; i < 4; i++)
          #pragma unroll
          for (int j = 0; j < 2; j++){
            acc[i + 4][j] = __builtin_amdgcn_mfma_f32_16x16x32_bf16(a[i][0], bA[j][0], acc[i + 4][j], 0, 0, 0);
            acc[i + 4][j] = __builtin_amdgcn_mfma_f32_16x16x32_bf16(a[i][1], bA[j][1], acc[i + 4][j], 0, 0, 0);
          }
        __builtin_amdgcn_s_setprio(0);
        __builtin_amdgcn_sched_barrier(0);
        if (stg) { asm volatile("s_waitcnt vmcnt(0)" ::: "memory"); }
        __builtin_amdgcn_s_barrier();
      }
    }
  }

  // ---------------- fused epilogue (LDS-staged) ----------------
  __syncthreads();
  u16* epi = SH + wave * 8192;
  int zone = n0 >> 10;          // 0=q, 1=k, 2=v, 3=g
  int n0l = n0 & 1023;
  int hh = (n0l >> 6) + wn;
  int b = m0 >> 11;
  int s0f = (m0 & 2047) + wm * 128;

  if (zone == 2){
    // V: epi rows = d (64 x 128 u16); chunk position = (s>>3)^(d&7) == vt's global layout
    #pragma unroll
    for (int j = 0; j < 4; j++){
      int d = j * 16 + l15;
      #pragma unroll
      for (int i = 0; i < 8; i++){
        int cs0 = i * 2 + (quad >> 1);            // logical s-chunk
        u16 pk[4];
        #pragma unroll
        for (int r = 0; r < 4; r++) pk[r] = f2bf(acc[i][j][r]);
        *(uint2*)&epi[d * 128 + ((cs0 ^ (d & 7)) * 8) + (quad & 1) * 4] = *(uint2*)pk;
      }
    }
    __syncthreads();
    int dl = lane >> 4, cl = lane & 15;
    size_t vbase = (size_t)((b << 4) + hh) * HD * S_LEN;
    #pragma unroll
    for (int it = 0; it < 16; it++){
      int d = it * 4 + dl;
      uint4 v = *(const uint4*)&epi[d * 128 + cl * 8];   // identity copy (layouts match)
      *(uint4*)&vt[vbase + (size_t)d * S_LEN + s0f + cl * 8] = v;
    }
  } else if (zone == 3){
    #pragma unroll
    for (int j = 0; j < 4; j++){
      int c0c = 2 * j + (l15 >> 3), o7 = l15 & 7;
      #pragma unroll
      for (int i = 0; i < 8; i++)
        #pragma unroll
        for (int r = 0; r < 4; r++){
          int row = i * 16 + quad * 4 + r;
          epi[row * 64 + ((c0c ^ (row & 7)) * 8) + o7] = f2bf(acc[i][j][r]);
        }
    }
    __syncthreads();
    int rl = lane >> 3, cl = lane & 7;
    #pragma unroll
    for (int it = 0; it < 16; it++){
      int row = it * 8 + rl;
      uint4 v = *(const uint4*)&epi[row * 64 + ((cl ^ (row & 7)) * 8)];
      *(uint4*)&gc[(size_t)(m0 + wm * 128 + row) * E_DIM + n0l + wn * 64 + cl * 8] = v;
    }
  } else {
    // q / k: chained-rotation rotary, staged in epi rows = s (128 x 64 u16),
    // chunk position (d>>3)^(s&7) == kr's global layout (and the bank-conflict fix for q)
    float scale = (zone == 1) ? 0.03125f : 1.0f;
    float sgn = (l15 & 1) ? 1.0f : -1.0f;
    #pragma unroll
    for (int j = 0; j < 4; j++){
      int d = j * 16 + l15;
      int c0c = 2 * j + (l15 >> 3), o7 = l15 & 7;
      float af = exp2f(-(float)(d >> 1) * (13.287712379549449f / 31.0f));
      float cs, sn, ca1, sa1, cb, sb_;
      __sincosf((float)(s0f + quad * 4) * af, &sn, &cs);
      __sincosf(af, &sa1, &ca1);
      __sincosf(13.0f * af, &sb_, &cb);
      #pragma unroll
      for (int i = 0; i < 8; i++)
        #pragma unroll
        for (int r = 0; r < 4; r++){
          int row = i * 16 + quad * 4 + r;
          float vv = acc[i][j][r] * scale;
          float p = __shfl_xor(vv, 1);
          float outv = vv * cs + sgn * p * sn;
          epi[row * 64 + ((c0c ^ (row & 7)) * 8) + o7] = f2bf(outv);
          float nc, ns;
          if (r < 3){ nc = cs * ca1 - sn * sa1; ns = sn * ca1 + cs * sa1; }
          else      { nc = cs * cb  - sn * sb_; ns = sn * cb  + cs * sb_; }
          cs = nc; sn = ns;
        }
    }
    __syncthreads();
    int rl = lane >> 3, cl = lane & 7;
    size_t qkbase = (size_t)((b << 4) + hh) * S_LEN + s0f;
    u16* dst = (zone == 0) ? qr : kr;
    #pragma unroll
    for (int it = 0; it < 16; it++){
      int row = it * 8 + rl;
      int rp = (zone == 0) ? (cl ^ (row & 7)) : cl;    // q deswizzles; k layouts match
      uint4 v = *(const uint4*)&epi[row * 64 + rp * 8];
      *(uint4*)&dst[(qkbase + row) * HD + cl * 8] = v;
    }
  }
}

// ---------------- retention (transpose world): S^T = K Q^T, O^T = V^T P^T ----------------
// OCCUPANCY v3 (R8 post-mortem: MfmaUtil 12.5 / VALU 39 / Occ 16% at 2 blocks/CU = latency-bound):
// 2-buffer __syncthreads ring (R7 proven; counted-vmcnt 3-ring was null here, m232 quadrant) with
// LDS cut to 50.4 KB -> 3 blocks/CU (160/50.4=3.17), __launch_bounds__(256,3). VGPR 88 fits
// 3 waves/SIMD. +50% resident waves for cross-block latency hiding (m114 mechanism).
// VALU trim: rc[r]=rfE*cbr precomputed per (e), chained by c16 (removes 32 mul/iter).
__global__ __launch_bounds__(256, 3) void retention_kernel(const u16* __restrict__ qr, const u16* __restrict__ kr,
                                                           const u16* __restrict__ vt,
                                                           u16* __restrict__ pO, u16* __restrict__ pBa){
  int bh = blockIdx.x;
  int qb = 15 - (int)blockIdx.y;
  int z  = blockIdx.z;
  int h = bh & 15;
  int q0 = qb * 128;
  __shared__ __align__(16) u16 Ks[2][4096];
  __shared__ __align__(16) u16 Vs[2][4096];
  __shared__ __align__(16) u16 Ps[128 * 72];
  int t = threadIdx.x, wave = t >> 6, lane = t & 63;
  int l15 = lane & 15, quad = lane >> 4, h8 = lane & 7;

  float decay = log1pf(-exp2f(-5.0f - (float)h));
  float negd = -decay;
  float estep = __expf(64.0f * negd);

  int qsE[2], rowb[2];
  #pragma unroll
  for (int e = 0; e < 2; e++){ rowb[e] = wave * 32 + e * 16; qsE[e] = q0 + rowb[e]; }

  bf16x8 qB[2][2];
  #pragma unroll
  for (int e = 0; e < 2; e++){
    size_t qrow = ((size_t)bh * S_LEN + qsE[e] + l15) * HD;
    qB[e][0] = *(const bf16x8*)&qr[qrow + quad * 8];
    qB[e][1] = *(const bf16x8*)&qr[qrow + 32 + quad * 8];
  }

  float win_f = 11.0f / negd;
  int win_i = (win_f > 2.1e9f) ? 0x7f000000 : (int)win_f;
  int nk = 2 * qb + 2;
  int z_lo = (z * nk) >> 2;
  int z_hi = (((z + 1) * nk) >> 2) - 1;
  int kb_lo = z_lo;
  {
    int jmin = q0 - win_i;
    if (jmin > z_lo * 64){ int wlo = jmin >> 6; kb_lo = wlo > z_lo ? wlo : z_lo; }
  }
  int k0s = kb_lo * 64;

  float em1d = expm1f(decay);
  float rfE[2]; int iE[2];
  #pragma unroll
  for (int e = 0; e < 2; e++){
    int i = qsE[e] + l15;
    iE[e] = i;
    float rowsum = expm1f((float)(i + 1) * decay) / em1d;
    rfE[e] = __expf((float)(i - k0s) * decay) * rsqrtf(rowsum);
  }
  float e1 = __expf(negd);
  float c16 = __expf(negd * 16.0f);
  float cbr[4];
  cbr[0] = __expf(negd * (float)(quad * 4));
  cbr[1] = cbr[0] * e1; cbr[2] = cbr[1] * e1; cbr[3] = cbr[2] * e1;

  f32x4 o[2][4];
  #pragma unroll
  for (int e = 0; e < 2; e++)
    #pragma unroll
    for (int dt = 0; dt < 4; dt++) o[e][dt] = (f32x4){0.f, 0.f, 0.f, 0.f};
  float babs[2] = {0.f, 0.f};

  const u16* krbh = kr + (size_t)bh * S_LEN * HD;
  const u16* vtbh = vt + (size_t)bh * HD * S_LEN;

  auto stKV = [&](int kb, int slot){
    int k0 = kb * 64;
    #pragma unroll
    for (int c = 0; c < 2; c++){
      int L = c * 256 + t;
      gl2lds16(krbh + (size_t)k0 * HD + L * 8, &Ks[slot][L * 8]);
    }
    #pragma unroll
    for (int c = 0; c < 2; c++){
      int L = c * 256 + t;
      gl2lds16(vtbh + (size_t)(L >> 3) * S_LEN + k0 + (L & 7) * 8, &Vs[slot][L * 8]);
    }
  };

  if (kb_lo <= z_hi){
    stKV(kb_lo, 0);
    __syncthreads();
    int cur = 0;
    for (int kb = kb_lo; kb <= z_hi; kb++){
      if (kb < z_hi) stKV(kb + 1, cur ^ 1);

      int k0 = kb * 64;
      const u16* KsC = &Ks[cur][0];
      const u16* VsC = &Vs[cur][0];

      bf16x8 kA0[4], kA1[4];
      #pragma unroll
      for (int ct = 0; ct < 4; ct++){
        int rw = (ct * 16 + l15) * 64;
        kA0[ct] = *(const bf16x8*)&KsC[rw + ((quad ^ h8) * 8)];
        kA1[ct] = *(const bf16x8*)&KsC[rw + (((quad + 4) ^ h8) * 8)];
      }
      #pragma unroll
      for (int e = 0; e < 2; e++){
        int qs = qsE[e];
        if (k0 <= qs + 15 && k0 + 63 >= qs - win_i){
          bool diag = (k0 + 64 > qs);
          float rc[4];
          #pragma unroll
          for (int r = 0; r < 4; r++) rc[r] = rfE[e] * cbr[r];
          #pragma unroll
          for (int ct = 0; ct < 4; ct++){
            f32x4 zacc = (f32x4){0.f, 0.f, 0.f, 0.f};
            zacc = __builtin_amdgcn_mfma_f32_16x16x32_bf16(kA0[ct], qB[e][0], zacc, 0, 0, 0);
            zacc = __builtin_amdgcn_mfma_f32_16x16x32_bf16(kA1[ct], qB[e][1], zacc, 0, 0, 0);
            u16 pk[4];
            #pragma unroll
            for (int r = 0; r < 4; r++){
              float p = zacc[r] * rc[r];
              if (diag && (k0 + ct * 16 + quad * 4 + r) > iE[e]) p = 0.f;
              babs[e] += fabsf(p);
              pk[r] = f2bf_fast(p);
              rc[r] *= c16;
            }
            u32 lo = (u32)pk[0] | ((u32)pk[1] << 16);
            u32 hi = (u32)pk[2] | ((u32)pk[3] << 16);
            *(uint2*)&Ps[(rowb[e] + l15) * 72 + ct * 16 + quad * 4] = make_uint2(lo, hi);
          }
        }
      }
      #pragma unroll
      for (int e = 0; e < 2; e++){
        int qs = qsE[e];
        if (k0 <= qs + 15 && k0 + 63 >= qs - win_i){
          bf16x8 pB0 = *(const bf16x8*)&Ps[(rowb[e] + l15) * 72 + quad * 8];
          bf16x8 pB1 = *(const bf16x8*)&Ps[(rowb[e] + l15) * 72 + 32 + quad * 8];
          #pragma unroll
          for (int dt = 0; dt < 4; dt++){
            int rw = (dt * 16 + l15) * 64;
            bf16x8 vA0 = *(const bf16x8*)&VsC[rw + ((quad ^ h8) * 8)];
            bf16x8 vA1 = *(const bf16x8*)&VsC[rw + (((quad + 4) ^ h8) * 8)];
            o[e][dt] = __builtin_amdgcn_mfma_f32_16x16x32_bf16(vA0, pB0, o[e][dt], 0, 0, 0);
            o[e][dt] = __builtin_amdgcn_mfma_f32_16x16x32_bf16(vA1, pB1, o[e][dt], 0, 0, 0);
          }
        }
      }
      #pragma unroll
      for (int e = 0; e < 2; e++) rfE[e] *= estep;
      __syncthreads();
      cur ^= 1;
    }
  }

  size_t slot = ((size_t)bh * 16 + qb) * 4 + z;
  u16* po = pO + slot * (4 * 128 * 16);
  #pragma unroll
  for (int e = 0; e < 2; e++){
    float bsum = babs[e];
    bsum += __shfl_xor(bsum, 16);
    bsum += __shfl_xor(bsum, 32);
    if (quad == 0) pBa[slot * 128 + rowb[e] + l15] = f2bf(bsum);
    #pragma unroll
    for (int dt = 0; dt < 4; dt++){
      u16 pk[4];
      #pragma unroll
      for (int r = 0; r < 4; r++) pk[r] = f2bf(o[e][dt][r]);
      *(uint2*)&po[(dt * 128 + rowb[e] + l15) * 16 + quad * 4] = *(uint2*)pk;
    }
  }
}

// ---------------- combine: sum 4 partials, denom clip, RMS, SiLU(g) ----------------
__global__ __launch_bounds__(128) void combine_kernel(const u16* __restrict__ pO, const u16* __restrict__ pBa,
                                                      const u16* __restrict__ gc, float* __restrict__ out){
  int bh = blockIdx.x, qb = blockIdx.y;
  int b = bh >> 4, h = bh & 15;
  int i = threadIdx.x;
  int s = qb * 128 + i;
  size_t s4 = ((size_t)bh * 16 + qb) * 4;
  float v[64];
  #pragma unroll
  for (int d = 0; d < 64; d++) v[d] = 0.f;
  float bsum = 0.f;
  #pragma unroll
  for (int z = 0; z < 4; z++){
    const u16* pz = pO + (s4 + z) * 8192;
    #pragma unroll
    for (int dt = 0; dt < 4; dt++){
      u16 a[16];
      *(uint4*)&a[0] = *(const uint4*)&pz[(dt * 128 + i) * 16];
      *(uint4*)&a[8] = *(const uint4*)&pz[(dt * 128 + i) * 16 + 8];
      #pragma unroll
      for (int c = 0; c < 16; c++) v[dt * 16 + c] += bf2f(a[c]);
    }
    bsum += bf2f(pBa[(s4 + z) * 128 + i]);
  }
  float dinv = 1.0f / fminf(fmaxf(bsum, 1.0f), 50000.0f);
  float ssq = 0.f;
  #pragma unroll
  for (int d = 0; d < 64; d++){ v[d] *= dinv; ssq += v[d] * v[d]; }
  float rms = rsqrtf(ssq * (1.0f / 64.0f) + 1e-6f);
  size_t gbase = ((size_t)b * S_LEN + s) * E_DIM + h * HD;
  u16 gu[64];
  #pragma unroll
  for (int c = 0; c < 8; c++) *(uint4*)&gu[c * 8] = *(const uint4*)&gc[gbase + c * 8];
  float ov[64];
  #pragma unroll
  for (int d = 0; d < 64; d++){
    float gv = bf2f(gu[d]);
    float sg = gv / (1.0f + __expf(-gv));
    ov[d] = v[d] * rms * sg;
  }
  float* obase = out + ((size_t)b * S_LEN + s) * E_DIM + h * HD;
  #pragma unroll
  for (int c = 0; c < 16; c++) *(float4*)&obase[c * 4] = *(float4*)&ov[c * 4];
}

extern "C" void kernel_launch(void* const* d_in, const int* in_sizes, int n_in,
                              void* d_out, int out_size, void* d_ws, size_t ws_size,
                              hipStream_t stream){
  const float* x  = (const float*)d_in[0];
  const float* Wq = (const float*)d_in[1];
  const float* Wk = (const float*)d_in[2];
  const float* Wv = (const float*)d_in[3];
  const float* Wg = (const float*)d_in[4];
  float* out = (float*)d_out;
  char* ws = (char*)d_ws;
  // ws layout (stream-ordered overlays), 64.5 MB peak:
  //   [0,8M):   xb (dead after gemm)  \__ overlaid by pO [0,32M) written by retention
  //   [8,16M):  WT (dead after gemm)  /
  //   [32,40M): qr    [40,48M): kr    [48,56M): vt   (gemm out, retention in)
  //   [56,64M): gc (live until combine)
  //   [64,64.5M): pBa
  u16* xb  = (u16*)(ws);
  u16* WT  = (u16*)(ws + (8ull  << 20));
  u16* pO  = (u16*)(ws);
  u16* qrp = (u16*)(ws + (32ull << 20));
  u16* krp = (u16*)(ws + (40ull << 20));
  u16* vtp = (u16*)(ws + (48ull << 20));
  u16* gcp = (u16*)(ws + (56ull << 20));
  u16* pBa = (u16*)(ws + (64ull << 20));

  prep_kernel     <<<dim3(16, 16, 8),  256, 0, stream>>>(x, Wq, Wk, Wv, Wg, xb, WT);
  gemm_kernel     <<<dim3(16, 16),     512, 0, stream>>>(xb, WT, qrp, krp, vtp, gcp);
  retention_kernel<<<dim3(32, 16, 4),  256, 0, stream>>>(qrp, krp, vtp, pO, pBa);
  combine_kernel  <<<dim3(32, 16),     128, 0, stream>>>(pO, pBa, gcp, out);
}

// Round 11
// 170.720 us; speedup vs baseline: 1.0629x; 1.0307x over previous
//
#include <hip/hip_runtime.h>

typedef unsigned short u16;
typedef unsigned int u32;
typedef __attribute__((ext_vector_type(8))) __bf16 bf16x8;
typedef __attribute__((ext_vector_type(4))) float f32x4;

#define B_SZ   2
#define S_LEN  2048
#define E_DIM  1024
#define NHEAD  16
#define HD     64
#define KDIM   1024

__device__ __forceinline__ float bf2f(u16 u){
  union { u32 i; float f; } c; c.i = ((u32)u) << 16; return c.f;
}
__device__ __forceinline__ u16 f2bf(float f){
  union { float f; u32 i; } c; c.f = f;
  return (u16)((c.i + 0x7FFFu + ((c.i >> 16) & 1u)) >> 16);
}
__device__ __forceinline__ u32 cvtpk_bf16(float lo, float hi){
  u32 r; asm("v_cvt_pk_bf16_f32 %0, %1, %2" : "=v"(r) : "v"(lo), "v"(hi)); return r;
}
__device__ __forceinline__ void gl2lds16(const void* g, void* l){
  __builtin_amdgcn_global_load_lds((const __attribute__((address_space(1))) void*)g,
                                   (__attribute__((address_space(3))) void*)l, 16, 0, 0);
}

// ---------------- prep: z<4 -> W_z transpose+cast (swizzled); z>=4 -> x cast (swizzled) ----------------
__global__ __launch_bounds__(256) void prep_kernel(const float* __restrict__ x,
                                                   const float* __restrict__ Wq, const float* __restrict__ Wk,
                                                   const float* __restrict__ Wv, const float* __restrict__ Wg,
                                                   u16* __restrict__ xb, u16* __restrict__ WT){
  __shared__ u16 tile[64][66];
  int z = blockIdx.z;
  int t = threadIdx.x;
  if (z < 4){
    const float* Ws[4] = {Wq, Wk, Wv, Wg};
    const float* W = Ws[z];
    int n0 = blockIdx.x * 64, k0 = blockIdx.y * 64;
    int r = t >> 2, cg = (t & 3) * 16;
    const float* src = W + (size_t)(k0 + r) * E_DIM + n0 + cg;
    float f[16];
    #pragma unroll
    for (int c = 0; c < 4; c++) *(float4*)&f[c * 4] = *(const float4*)&src[c * 4];
    #pragma unroll
    for (int i = 0; i < 16; i++) tile[r][cg + i] = f2bf(f[i]);
    __syncthreads();
    u16 ov[16];
    #pragma unroll
    for (int i = 0; i < 16; i++) ov[i] = tile[cg + i][r];
    int n7 = r & 7, cb = cg >> 3;
    u16* dst = WT + (size_t)(z * E_DIM + n0 + r) * KDIM + k0;
    *(uint4*)&dst[(cb ^ n7) * 8]       = *(uint4*)&ov[0];
    *(uint4*)&dst[((cb + 1) ^ n7) * 8] = *(uint4*)&ov[8];
  } else {
    int blk = (z - 4) * 256 + blockIdx.y * 16 + blockIdx.x;
    size_t flat = ((size_t)blk * 256 + t) * 16;
    int m7 = (int)((flat >> 10) & 7);
    int cb = (int)((flat >> 3) & 7);
    size_t tl = flat & ~(size_t)63;
    float f[16];
    #pragma unroll
    for (int c = 0; c < 4; c++) *(float4*)&f[c * 4] = *(const float4*)&x[flat + c * 4];
    u16 o[16];
    #pragma unroll
    for (int i = 0; i < 16; i++) o[i] = f2bf(f[i]);
    *(uint4*)&xb[tl + ((cb ^ m7) * 8)]       = *(uint4*)&o[0];
    *(uint4*)&xb[tl + (((cb + 1) ^ m7) * 8)] = *(uint4*)&o[8];
  }
}

// ---------------- fused QKVG GEMM + rotary/transpose epilogue (LDS-staged stores) ----------------
// Main loop: 256x256 tile, BK=64, Gray-code 3-subphase; safe gating (single vmcnt(0) at XC-end,
// R6 race post-mortem). Epilogue: chained-rotation rotary + LDS-staged coalesced stores.
__global__ __launch_bounds__(512, 2) void gemm_kernel(const u16* __restrict__ A, const u16* __restrict__ Bt,
                                                      u16* __restrict__ qr, u16* __restrict__ kr,
                                                      u16* __restrict__ vt, u16* __restrict__ gc){
  __shared__ __align__(16) u16 SH[65536];   // 128 KB: main loop As/Bs; epilogue staging
  int m0 = blockIdx.y * 256, n0 = blockIdx.x * 256;
  int t = threadIdx.x;
  int wave = t >> 6, lane = t & 63;
  int l15 = lane & 15, quad = lane >> 4, h8 = lane & 7;
  int wm = wave >> 2, wn = wave & 3;

  f32x4 acc[8][4];
  #pragma unroll
  for (int i = 0; i < 8; i++)
    #pragma unroll
    for (int j = 0; j < 4; j++) acc[i][j] = (f32x4){0.f, 0.f, 0.f, 0.f};

  auto Aoff = [&](int buf, int half) -> int { return (buf * 2 + half) * 8192; };
  auto Boff = [&](int buf, int half) -> int { return 32768 + (buf * 2 + half) * 8192; };

  auto stA = [&](int buf, int half, int kt){
    const u16* src = A + (size_t)(m0 + half * 128) * KDIM + kt * 64;
    #pragma unroll
    for (int c = 0; c < 2; c++){
      int L = c * 512 + t;
      gl2lds16(src + (size_t)(L >> 3) * KDIM + (L & 7) * 8, &SH[Aoff(buf, half) + L * 8]);
    }
  };
  auto stB = [&](int buf, int half, int kt){
    const u16* src = Bt + (size_t)(n0 + half * 128) * KDIM + kt * 64;
    #pragma unroll
    for (int c = 0; c < 2; c++){
      int L = c * 512 + t;
      gl2lds16(src + (size_t)(L >> 3) * KDIM + (L & 7) * 8, &SH[Boff(buf, half) + L * 8]);
    }
  };
  auto ldA = [&](int buf, int i, int ks) -> bf16x8 {
    int r = i * 16 + l15;
    return *(const bf16x8*)&SH[Aoff(buf, wm) + r * 64 + (((ks * 4 + quad) ^ h8) * 8)];
  };
  auto ldB = [&](int buf, int j, int ks) -> bf16x8 {
    int c = (wn & 1) * 64 + j * 16 + l15;
    return *(const bf16x8*)&SH[Boff(buf, wn >> 1) + c * 64 + (((ks * 4 + quad) ^ h8) * 8)];
  };

  stA(0, 0, 0); stB(0, 0, 0); stA(0, 1, 0); stB(0, 1, 0);
  asm volatile("s_waitcnt vmcnt(0)" ::: "memory");
  __builtin_amdgcn_s_barrier();

  bf16x8 a[4][2];
  bf16x8 bA[2][2];
  bf16x8 bB[2][2];

  for (int t2 = 0; t2 < 8; ++t2){
    int kt0 = 2 * t2;
    bool more = (t2 < 7);

    #pragma unroll
    for (int half = 0; half < 2; ++half){
      int buf = half;
      bool stg = (buf == 0) || more;
      // ---------- XA: a0 + b0 | stage oth.Ah0 + oth.Bh0 | q1 ----------
      {
        #pragma unroll
        for (int i = 0; i < 4; i++){ a[i][0] = ldA(buf, i, 0); a[i][1] = ldA(buf, i, 1); }
        #pragma unroll
        for (int j = 0; j < 2; j++){ bA[j][0] = ldB(buf, j, 0); bA[j][1] = ldB(buf, j, 1); }
        if (buf == 0){ stA(1, 0, kt0 + 1); stB(1, 0, kt0 + 1); }
        else if (more){ stA(0, 0, kt0 + 2); stB(0, 0, kt0 + 2); }
        __builtin_amdgcn_sched_barrier(0);
        __builtin_amdgcn_s_barrier();
        asm volatile("s_waitcnt lgkmcnt(0)" ::: "memory");
        __builtin_amdgcn_sched_barrier(0);
        __builtin_amdgcn_s_setprio(1);
        #pragma unroll
        for (int i = 0; i < 4; i++)
          #pragma unroll
          for (int j = 0; j < 2; j++){
            acc[i][j] = __builtin_amdgcn_mfma_f32_16x16x32_bf16(a[i][0], bA[j][0], acc[i][j], 0, 0, 0);
            acc[i][j] = __builtin_amdgcn_mfma_f32_16x16x32_bf16(a[i][1], bA[j][1], acc[i][j], 0, 0, 0);
          }
        __builtin_amdgcn_s_setprio(0);
        __builtin_amdgcn_sched_barrier(0);
        __builtin_amdgcn_s_barrier();
      }
      // ---------- XB: b1 | stage oth.Ah1 + oth.Bh1 | q2 ----------
      {
        #pragma unroll
        for (int j = 0; j < 2; j++){ bB[j][0] = ldB(buf, j + 2, 0); bB[j][1] = ldB(buf, j + 2, 1); }
        if (buf == 0){ stA(1, 1, kt0 + 1); stB(1, 1, kt0 + 1); }
        else if (more){ stA(0, 1, kt0 + 2); stB(0, 1, kt0 + 2); }
        __builtin_amdgcn_sched_barrier(0);
        __builtin_amdgcn_s_barrier();
        asm volatile("s_waitcnt lgkmcnt(0)" ::: "memory");
        __builtin_amdgcn_sched_barrier(0);
        __builtin_amdgcn_s_setprio(1);
        #pragma unroll
        for (int i = 0; i < 4; i++)
          #pragma unroll
          for (int j = 0; j < 2; j++){
            acc[i][j + 2] = __builtin_amdgcn_mfma_f32_16x16x32_bf16(a[i][0], bB[j][0], acc[i][j + 2], 0, 0, 0);
            acc[i][j + 2] = __builtin_amdgcn_mfma_f32_16x16x32_bf16(a[i][1], bB[j][1], acc[i][j + 2], 0, 0, 0);
          }
        __builtin_amdgcn_s_setprio(0);
        __builtin_amdgcn_sched_barrier(0);
        __builtin_amdgcn_s_barrier();
      }
      // ---------- XC: a1 | no stage | q3 + q4 | vmcnt(0) while stages exist ----------
      {
        #pragma unroll
        for (int i = 0; i < 4; i++){ a[i][0] = ldA(buf, i + 4, 0); a[i][1] = ldA(buf, i + 4, 1); }
        __builtin_amdgcn_sched_barrier(0);
        __builtin_amdgcn_s_barrier();
        asm volatile("s_waitcnt lgkmcnt(0)" ::: "memory");
        __builtin_amdgcn_sched_barrier(0);
        __builtin_amdgcn_s_setprio(1);
        #pragma unroll
        for (int i = 0; i < 4; i++)
          #pragma unroll
          for (int j = 0; j < 2; j++){
            acc[i + 4][j + 2] = __builtin_amdgcn_mfma_f32_16x16x32_bf16(a[i][0], bB[j][0], acc[i + 4][j + 2], 0, 0, 0);
            acc[i + 4][j + 2] = __builtin_amdgcn_mfma_f32_16x16x32_bf16(a[i][1], bB[j][1], acc[i + 4][j + 2], 0, 0, 0);
          }
        #pragma unroll
        for (int i = 0; i < 4; i++)
          #pragma unroll
          for (int j = 0; j < 2; j++){
            acc[i + 4][j] = __builtin_amdgcn_mfma_f32_16x16x32_bf16(a[i][0], bA[j][0], acc[i + 4][j], 0, 0, 0);
            acc[i + 4][j] = __builtin_amdgcn_mfma_f32_16x16x32_bf16(a[i][1], bA[j][1], acc[i + 4][j], 0, 0, 0);
          }
        __builtin_amdgcn_s_setprio(0);
        __builtin_amdgcn_sched_barrier(0);
        if (stg) { asm volatile("s_waitcnt vmcnt(0)" ::: "memory"); }
        __builtin_amdgcn_s_barrier();
      }
    }
  }

  // ---------------- fused epilogue (LDS-staged) ----------------
  __syncthreads();
  u16* epi = SH + wave * 8192;
  int zone = n0 >> 10;          // 0=q, 1=k, 2=v, 3=g
  int n0l = n0 & 1023;
  int hh = (n0l >> 6) + wn;
  int b = m0 >> 11;
  int s0f = (m0 & 2047) + wm * 128;

  if (zone == 2){
    // V: epi rows = d (64 x 128 u16); chunk position = (s>>3)^(d&7) == vt's global layout
    #pragma unroll
    for (int j = 0; j < 4; j++){
      int d = j * 16 + l15;
      #pragma unroll
      for (int i = 0; i < 8; i++){
        int cs0 = i * 2 + (quad >> 1);            // logical s-chunk
        u16 pk[4];
        #pragma unroll
        for (int r = 0; r < 4; r++) pk[r] = f2bf(acc[i][j][r]);
        *(uint2*)&epi[d * 128 + ((cs0 ^ (d & 7)) * 8) + (quad & 1) * 4] = *(uint2*)pk;
      }
    }
    __syncthreads();
    int dl = lane >> 4, cl = lane & 15;
    size_t vbase = (size_t)((b << 4) + hh) * HD * S_LEN;
    #pragma unroll
    for (int it = 0; it < 16; it++){
      int d = it * 4 + dl;
      uint4 v = *(const uint4*)&epi[d * 128 + cl * 8];   // identity copy (layouts match)
      *(uint4*)&vt[vbase + (size_t)d * S_LEN + s0f + cl * 8] = v;
    }
  } else if (zone == 3){
    #pragma unroll
    for (int j = 0; j < 4; j++){
      int c0c = 2 * j + (l15 >> 3), o7 = l15 & 7;
      #pragma unroll
      for (int i = 0; i < 8; i++)
        #pragma unroll
        for (int r = 0; r < 4; r++){
          int row = i * 16 + quad * 4 + r;
          epi[row * 64 + ((c0c ^ (row & 7)) * 8) + o7] = f2bf(acc[i][j][r]);
        }
    }
    __syncthreads();
    int rl = lane >> 3, cl = lane & 7;
    #pragma unroll
    for (int it = 0; it < 16; it++){
      int row = it * 8 + rl;
      uint4 v = *(const uint4*)&epi[row * 64 + ((cl ^ (row & 7)) * 8)];
      *(uint4*)&gc[(size_t)(m0 + wm * 128 + row) * E_DIM + n0l + wn * 64 + cl * 8] = v;
    }
  } else {
    // q / k: chained-rotation rotary, staged in epi rows = s (128 x 64 u16),
    // chunk position (d>>3)^(s&7) == kr's global layout (and the bank-conflict fix for q)
    float scale = (zone == 1) ? 0.03125f : 1.0f;
    float sgn = (l15 & 1) ? 1.0f : -1.0f;
    #pragma unroll
    for (int j = 0; j < 4; j++){
      int d = j * 16 + l15;
      int c0c = 2 * j + (l15 >> 3), o7 = l15 & 7;
      float af = exp2f(-(float)(d >> 1) * (13.287712379549449f / 31.0f));
      float cs, sn, ca1, sa1, cb, sb_;
      __sincosf((float)(s0f + quad * 4) * af, &sn, &cs);
      __sincosf(af, &sa1, &ca1);
      __sincosf(13.0f * af, &sb_, &cb);
      #pragma unroll
      for (int i = 0; i < 8; i++)
        #pragma unroll
        for (int r = 0; r < 4; r++){
          int row = i * 16 + quad * 4 + r;
          float vv = acc[i][j][r] * scale;
          float p = __shfl_xor(vv, 1);
          float outv = vv * cs + sgn * p * sn;
          epi[row * 64 + ((c0c ^ (row & 7)) * 8) + o7] = f2bf(outv);
          float nc, ns;
          if (r < 3){ nc = cs * ca1 - sn * sa1; ns = sn * ca1 + cs * sa1; }
          else      { nc = cs * cb  - sn * sb_; ns = sn * cb  + cs * sb_; }
          cs = nc; sn = ns;
        }
    }
    __syncthreads();
    int rl = lane >> 3, cl = lane & 7;
    size_t qkbase = (size_t)((b << 4) + hh) * S_LEN + s0f;
    u16* dst = (zone == 0) ? qr : kr;
    #pragma unroll
    for (int it = 0; it < 16; it++){
      int row = it * 8 + rl;
      int rp = (zone == 0) ? (cl ^ (row & 7)) : cl;    // q deswizzles; k layouts match
      uint4 v = *(const uint4*)&epi[row * 64 + rp * 8];
      *(uint4*)&dst[(qkbase + row) * HD + cl * 8] = v;
    }
  }
}

// ---------------- retention (transpose world): S^T = K Q^T, O^T = V^T P^T ----------------
// R9 base (2-buffer ring, 50.4 KB LDS -> 3 blocks/CU) + R10 VALU diet:
//  - EMPTY-SLOT SKIP: window-clamped (kb_lo > z_hi) blocks return without writing pO/pBa;
//    combine reproduces the identical predicate and skips those slots (saves ~25-30% pO traffic).
//  - DIAG HOIST: diag is wave-uniform; non-diag tiles (~85%) run a mask-free P loop.
//  - v_cvt_pk_bf16_f32 (1 inst / 2 elems) replaces the manual f2bf pack (~6 inst / 2 elems).
// R8 counters showed VALUBusy 39% vs MfmaUtil 12.5% -- P-scale VALU is the fat, these cut it.
__global__ __launch_bounds__(256, 3) void retention_kernel(const u16* __restrict__ qr, const u16* __restrict__ kr,
                                                           const u16* __restrict__ vt,
                                                           u16* __restrict__ pO, u16* __restrict__ pBa){
  __shared__ __align__(16) u16 Ks[2][4096];
  __shared__ __align__(16) u16 Vs[2][4096];
  __shared__ __align__(16) u16 Ps[128 * 72];
  int bh = blockIdx.x;
  int qb = 15 - (int)blockIdx.y;
  int z  = blockIdx.z;
  int h = bh & 15;
  int q0 = qb * 128;

  // ---- window/empty predicate (EXACT same code in combine_kernel) ----
  float decay = log1pf(-exp2f(-5.0f - (float)h));
  float negd = -decay;
  float win_f = 11.0f / negd;
  int win_i = (win_f > 2.1e9f) ? 0x7f000000 : (int)win_f;
  int nk = 2 * qb + 2;
  int z_lo = (z * nk) >> 2;
  int z_hi = (((z + 1) * nk) >> 2) - 1;
  int kb_lo = z_lo;
  {
    int jmin = q0 - win_i;
    if (jmin > z_lo * 64){ int wlo = jmin >> 6; kb_lo = wlo > z_lo ? wlo : z_lo; }
  }
  if (kb_lo > z_hi) return;          // fully-empty slot: combine skips it too

  int t = threadIdx.x, wave = t >> 6, lane = t & 63;
  int l15 = lane & 15, quad = lane >> 4, h8 = lane & 7;
  float estep = __expf(64.0f * negd);

  int qsE[2], rowb[2];
  #pragma unroll
  for (int e = 0; e < 2; e++){ rowb[e] = wave * 32 + e * 16; qsE[e] = q0 + rowb[e]; }

  bf16x8 qB[2][2];
  #pragma unroll
  for (int e = 0; e < 2; e++){
    size_t qrow = ((size_t)bh * S_LEN + qsE[e] + l15) * HD;
    qB[e][0] = *(const bf16x8*)&qr[qrow + quad * 8];
    qB[e][1] = *(const bf16x8*)&qr[qrow + 32 + quad * 8];
  }

  int k0s = kb_lo * 64;
  float em1d = expm1f(decay);
  float rfE[2]; int iE[2];
  #pragma unroll
  for (int e = 0; e < 2; e++){
    int i = qsE[e] + l15;
    iE[e] = i;
    float rowsum = expm1f((float)(i + 1) * decay) / em1d;
    rfE[e] = __expf((float)(i - k0s) * decay) * rsqrtf(rowsum);
  }
  float e1 = __expf(negd);
  float c16 = __expf(negd * 16.0f);
  float cbr[4];
  cbr[0] = __expf(negd * (float)(quad * 4));
  cbr[1] = cbr[0] * e1; cbr[2] = cbr[1] * e1; cbr[3] = cbr[2] * e1;

  f32x4 o[2][4];
  #pragma unroll
  for (int e = 0; e < 2; e++)
    #pragma unroll
    for (int dt = 0; dt < 4; dt++) o[e][dt] = (f32x4){0.f, 0.f, 0.f, 0.f};
  float babs[2] = {0.f, 0.f};

  const u16* krbh = kr + (size_t)bh * S_LEN * HD;
  const u16* vtbh = vt + (size_t)bh * HD * S_LEN;

  auto stKV = [&](int kb, int slot){
    int k0 = kb * 64;
    #pragma unroll
    for (int c = 0; c < 2; c++){
      int L = c * 256 + t;
      gl2lds16(krbh + (size_t)k0 * HD + L * 8, &Ks[slot][L * 8]);
    }
    #pragma unroll
    for (int c = 0; c < 2; c++){
      int L = c * 256 + t;
      gl2lds16(vtbh + (size_t)(L >> 3) * S_LEN + k0 + (L & 7) * 8, &Vs[slot][L * 8]);
    }
  };

  stKV(kb_lo, 0);
  __syncthreads();
  int cur = 0;
  for (int kb = kb_lo; kb <= z_hi; kb++){
    if (kb < z_hi) stKV(kb + 1, cur ^ 1);

    int k0 = kb * 64;
    const u16* KsC = &Ks[cur][0];
    const u16* VsC = &Vs[cur][0];

    bf16x8 kA0[4], kA1[4];
    #pragma unroll
    for (int ct = 0; ct < 4; ct++){
      int rw = (ct * 16 + l15) * 64;
      kA0[ct] = *(const bf16x8*)&KsC[rw + ((quad ^ h8) * 8)];
      kA1[ct] = *(const bf16x8*)&KsC[rw + (((quad + 4) ^ h8) * 8)];
    }
    #pragma unroll
    for (int e = 0; e < 2; e++){
      int qs = qsE[e];
      if (k0 <= qs + 15 && k0 + 63 >= qs - win_i){
        float rc0 = rfE[e] * cbr[0], rc1 = rfE[e] * cbr[1];
        float rc2 = rfE[e] * cbr[2], rc3 = rfE[e] * cbr[3];
        if (k0 + 64 <= qs){
          // non-diagonal tile: mask-free P loop (wave-uniform branch)
          #pragma unroll
          for (int ct = 0; ct < 4; ct++){
            f32x4 zacc = (f32x4){0.f, 0.f, 0.f, 0.f};
            zacc = __builtin_amdgcn_mfma_f32_16x16x32_bf16(kA0[ct], qB[e][0], zacc, 0, 0, 0);
            zacc = __builtin_amdgcn_mfma_f32_16x16x32_bf16(kA1[ct], qB[e][1], zacc, 0, 0, 0);
            float p0 = zacc[0] * rc0, p1 = zacc[1] * rc1, p2 = zacc[2] * rc2, p3 = zacc[3] * rc3;
            babs[e] += fabsf(p0); babs[e] += fabsf(p1); babs[e] += fabsf(p2); babs[e] += fabsf(p3);
            u32 lo = cvtpk_bf16(p0, p1), hi = cvtpk_bf16(p2, p3);
            rc0 *= c16; rc1 *= c16; rc2 *= c16; rc3 *= c16;
            *(uint2*)&Ps[(rowb[e] + l15) * 72 + ct * 16 + quad * 4] = make_uint2(lo, hi);
          }
        } else {
          // diagonal tile: causal mask applied per element
          #pragma unroll
          for (int ct = 0; ct < 4; ct++){
            f32x4 zacc = (f32x4){0.f, 0.f, 0.f, 0.f};
            zacc = __builtin_amdgcn_mfma_f32_16x16x32_bf16(kA0[ct], qB[e][0], zacc, 0, 0, 0);
            zacc = __builtin_amdgcn_mfma_f32_16x16x32_bf16(kA1[ct], qB[e][1], zacc, 0, 0, 0);
            int kbase = k0 + ct * 16 + quad * 4;
            float p0 = zacc[0] * rc0, p1 = zacc[1] * rc1, p2 = zacc[2] * rc2, p3 = zacc[3] * rc3;
            if (kbase + 0 > iE[e]) p0 = 0.f;
            if (kbase + 1 > iE[e]) p1 = 0.f;
            if (kbase + 2 > iE[e]) p2 = 0.f;
            if (kbase + 3 > iE[e]) p3 = 0.f;
            babs[e] += fabsf(p0); babs[e] += fabsf(p1); babs[e] += fabsf(p2); babs[e] += fabsf(p3);
            u32 lo = cvtpk_bf16(p0, p1), hi = cvtpk_bf16(p2, p3);
            rc0 *= c16; rc1 *= c16; rc2 *= c16; rc3 *= c16;
            *(uint2*)&Ps[(rowb[e] + l15) * 72 + ct * 16 + quad * 4] = make_uint2(lo, hi);
          }
        }
      }
    }
    #pragma unroll
    for (int e = 0; e < 2; e++){
      int qs = qsE[e];
      if (k0 <= qs + 15 && k0 + 63 >= qs - win_i){
        bf16x8 pB0 = *(const bf16x8*)&Ps[(rowb[e] + l15) * 72 + quad * 8];
        bf16x8 pB1 = *(const bf16x8*)&Ps[(rowb[e] + l15) * 72 + 32 + quad * 8];
        #pragma unroll
        for (int dt = 0; dt < 4; dt++){
          int rw = (dt * 16 + l15) * 64;
          bf16x8 vA0 = *(const bf16x8*)&VsC[rw + ((quad ^ h8) * 8)];
          bf16x8 vA1 = *(const bf16x8*)&VsC[rw + (((quad + 4) ^ h8) * 8)];
          o[e][dt] = __builtin_amdgcn_mfma_f32_16x16x32_bf16(vA0, pB0, o[e][dt], 0, 0, 0);
          o[e][dt] = __builtin_amdgcn_mfma_f32_16x16x32_bf16(vA1, pB1, o[e][dt], 0, 0, 0);
        }
      }
    }
    #pragma unroll
    for (int e = 0; e < 2; e++) rfE[e] *= estep;
    __syncthreads();
    cur ^= 1;
  }

  size_t slot = ((size_t)bh * 16 + qb) * 4 + z;
  u16* po = pO + slot * (4 * 128 * 16);
  #pragma unroll
  for (int e = 0; e < 2; e++){
    float bsum = babs[e];
    bsum += __shfl_xor(bsum, 16);
    bsum += __shfl_xor(bsum, 32);
    if (quad == 0) pBa[slot * 128 + rowb[e] + l15] = f2bf(bsum);
    #pragma unroll
    for (int dt = 0; dt < 4; dt++){
      u16 pk[4];
      #pragma unroll
      for (int r = 0; r < 4; r++) pk[r] = f2bf(o[e][dt][r]);
      *(uint2*)&po[(dt * 128 + rowb[e] + l15) * 16 + quad * 4] = *(uint2*)pk;
    }
  }
}

// ---------------- combine: sum non-empty partials, denom clip, RMS, SiLU(g) ----------------
// Empty-slot predicate replicated EXACTLY from retention_kernel (same float/int ops, same order);
// retention early-returns on empty slots without writing pO/pBa, so we must not read them.
__global__ __launch_bounds__(128) void combine_kernel(const u16* __restrict__ pO, const u16* __restrict__ pBa,
                                                      const u16* __restrict__ gc, float* __restrict__ out){
  int bh = blockIdx.x, qb = blockIdx.y;
  int b = bh >> 4, h = bh & 15;
  int i = threadIdx.x;
  int s = qb * 128 + i;
  size_t s4 = ((size_t)bh * 16 + qb) * 4;

  float decay = log1pf(-exp2f(-5.0f - (float)h));
  float negd = -decay;
  float win_f = 11.0f / negd;
  int win_i = (win_f > 2.1e9f) ? 0x7f000000 : (int)win_f;
  int nk = 2 * qb + 2;
  int q0 = qb * 128;

  float v[64];
  #pragma unroll
  for (int d = 0; d < 64; d++) v[d] = 0.f;
  float bsum = 0.f;
  #pragma unroll
  for (int z = 0; z < 4; z++){
    int z_lo = (z * nk) >> 2;
    int z_hi = (((z + 1) * nk) >> 2) - 1;
    int kb_lo = z_lo;
    {
      int jmin = q0 - win_i;
      if (jmin > z_lo * 64){ int wlo = jmin >> 6; kb_lo = wlo > z_lo ? wlo : z_lo; }
    }
    if (kb_lo > z_hi) continue;       // slot never written by retention
    const u16* pz = pO + (s4 + z) * 8192;
    #pragma unroll
    for (int dt = 0; dt < 4; dt++){
      u16 a[16];
      *(uint4*)&a[0] = *(const uint4*)&pz[(dt * 128 + i) * 16];
      *(uint4*)&a[8] = *(const uint4*)&pz[(dt * 128 + i) * 16 + 8];
      #pragma unroll
      for (int c = 0; c < 16; c++) v[dt * 16 + c] += bf2f(a[c]);
    }
    bsum += bf2f(pBa[(s4 + z) * 128 + i]);
  }
  float dinv = 1.0f / fminf(fmaxf(bsum, 1.0f), 50000.0f);
  float ssq = 0.f;
  #pragma unroll
  for (int d = 0; d < 64; d++){ v[d] *= dinv; ssq += v[d] * v[d]; }
  float rms = rsqrtf(ssq * (1.0f / 64.0f) + 1e-6f);
  size_t gbase = ((size_t)b * S_LEN + s) * E_DIM + h * HD;
  u16 gu[64];
  #pragma unroll
  for (int c = 0; c < 8; c++) *(uint4*)&gu[c * 8] = *(const uint4*)&gc[gbase + c * 8];
  float ov[64];
  #pragma unroll
  for (int d = 0; d < 64; d++){
    float gv = bf2f(gu[d]);
    float sg = gv / (1.0f + __expf(-gv));
    ov[d] = v[d] * rms * sg;
  }
  float* obase = out + ((size_t)b * S_LEN + s) * E_DIM + h * HD;
  #pragma unroll
  for (int c = 0; c < 16; c++) *(float4*)&obase[c * 4] = *(float4*)&ov[c * 4];
}

extern "C" void kernel_launch(void* const* d_in, const int* in_sizes, int n_in,
                              void* d_out, int out_size, void* d_ws, size_t ws_size,
                              hipStream_t stream){
  const float* x  = (const float*)d_in[0];
  const float* Wq = (const float*)d_in[1];
  const float* Wk = (const float*)d_in[2];
  const float* Wv = (const float*)d_in[3];
  const float* Wg = (const float*)d_in[4];
  float* out = (float*)d_out;
  char* ws = (char*)d_ws;
  // ws layout (stream-ordered overlays), 64.5 MB peak:
  //   [0,8M):   xb (dead after gemm)  \__ overlaid by pO [0,32M) written by retention
  //   [8,16M):  WT (dead after gemm)  /
  //   [32,40M): qr    [40,48M): kr    [48,56M): vt   (gemm out, retention in)
  //   [56,64M): gc (live until combine)
  //   [64,64.5M): pBa
  u16* xb  = (u16*)(ws);
  u16* WT  = (u16*)(ws + (8ull  << 20));
  u16* pO  = (u16*)(ws);
  u16* qrp = (u16*)(ws + (32ull << 20));
  u16* krp = (u16*)(ws + (40ull << 20));
  u16* vtp = (u16*)(ws + (48ull << 20));
  u16* gcp = (u16*)(ws + (56ull << 20));
  u16* pBa = (u16*)(ws + (64ull << 20));

  prep_kernel     <<<dim3(16, 16, 8),  256, 0, stream>>>(x, Wq, Wk, Wv, Wg, xb, WT);
  gemm_kernel     <<<dim3(16, 16),     512, 0, stream>>>(xb, WT, qrp, krp, vtp, gcp);
  retention_kernel<<<dim3(32, 16, 4),  256, 0, stream>>>(qrp, krp, vtp, pO, pBa);
  combine_kernel  <<<dim3(32, 16),     128, 0, stream>>>(pO, pBa, gcp, out);
}